// Round 13
// baseline (240.712 us; speedup 1.0000x reference)
//
#include <hip/hip_runtime.h>

#define N_NODES 50000
#define N_EDGES 800000
#define DIM 64
#define NUM_GRAPHS 64
#define NPART 8
#define PART_NODES 6250   // N_NODES / NPART exactly

typedef unsigned short u16;
typedef unsigned int u32;

__device__ __forceinline__ u16 bf16_rne(float f) {
  u32 u = __float_as_uint(f);
  u32 r = (u + 0x7fffu + ((u >> 16) & 1u)) >> 16;
  return (u16)r;
}

// ---- init: zero cnt + convert x -> bf16 ----
__global__ void init_kernel(int* __restrict__ cnt,
                            const float* __restrict__ x, u16* __restrict__ xh) {
  int i = blockIdx.x * blockDim.x + threadIdx.x;
  if (i < N_NODES) cnt[i] = 0;
  int stride = gridDim.x * blockDim.x;
  for (int k = i; k < N_NODES * DIM / 4; k += stride) {
    float4 v = reinterpret_cast<const float4*>(x)[k];
    ushort4 o;
    o.x = bf16_rne(v.x); o.y = bf16_rne(v.y);
    o.z = bf16_rne(v.z); o.w = bf16_rne(v.w);
    reinterpret_cast<ushort4*>(xh)[k] = o;
  }
}

// ---- degree count: single pass, grid-stride ----
__global__ void count_deg_kernel(const int* __restrict__ dst, int* __restrict__ cnt, int E) {
  int stride = gridDim.x * blockDim.x;
  for (int e = blockIdx.x * blockDim.x + threadIdx.x; e < E; e += stride)
    atomicAdd(&cnt[dst[e]], 1);
}

// ---- scan phase A: block-local exclusive scan of cnt, block sums, fused dis ----
__global__ void scanA_kernel(const int* __restrict__ cnt, int* __restrict__ rowptr,
                             int* __restrict__ bsum, float* __restrict__ dis, int N) {
  __shared__ int wsum[16];
  int i = blockIdx.x * 1024 + threadIdx.x;
  int lane = threadIdx.x & 63, wid = threadIdx.x >> 6;
  int v = (i < N) ? cnt[i] : 0;
  if (i < N) dis[i] = rsqrtf((float)(v + 1));
  int sv = v;
  #pragma unroll
  for (int off = 1; off < 64; off <<= 1) {
    int t = __shfl_up(sv, off, 64);
    if (lane >= off) sv += t;
  }
  if (lane == 63) wsum[wid] = sv;
  __syncthreads();
  if (wid == 0) {
    int wv = (lane < 16) ? wsum[lane] : 0;
    #pragma unroll
    for (int off = 1; off < 16; off <<= 1) {
      int t = __shfl_up(wv, off, 64);
      if (lane >= off) wv += t;
    }
    if (lane < 16) wsum[lane] = wv;
  }
  __syncthreads();
  if (i < N) rowptr[i] = (wid ? wsum[wid - 1] : 0) + (sv - v);
  if (threadIdx.x == 1023) bsum[blockIdx.x] = wsum[15];
}

// ---- scan phase C (B folded in) ----
__global__ void scanC_kernel(int* __restrict__ rowptr, const int* __restrict__ bsum,
                             int* __restrict__ cursor, int nb, int N) {
  __shared__ int s_off;
  __shared__ int s_total;
  int b = blockIdx.x;
  if (threadIdx.x < 64) {
    int t = threadIdx.x;
    int v = (t < nb) ? bsum[t] : 0;
    #pragma unroll
    for (int off = 1; off < 64; off <<= 1) {
      int u = __shfl_up(v, off, 64);
      if (t >= off) v += u;
    }
    if (t == (b == 0 ? 0 : b - 1)) s_off = (b == 0) ? 0 : v;
    if (t == nb - 1) s_total = v;
  }
  __syncthreads();
  int i = b * 1024 + threadIdx.x;
  if (i < N) {
    int r = rowptr[i] + s_off;
    rowptr[i] = r;
    cursor[i] = r;
  }
  if (b == 0 && threadIdx.x == 0) rowptr[N] = s_total;
}

// ---- fill CSR, XCD-partitioned; stores (src, dis[src]) pairs ----
__global__ void fill_kernel(const int* __restrict__ src, const int* __restrict__ dst,
                            const float* __restrict__ dis,
                            int* __restrict__ cursor, int2* __restrict__ epair, int E) {
  int p = blockIdx.x & 7;
  int lo = p * PART_NODES, hi = lo + PART_NODES;
  int stride = (gridDim.x >> 3) * blockDim.x;
  for (int e = (blockIdx.x >> 3) * blockDim.x + threadIdx.x; e < E; e += stride) {
    int d = dst[e];
    if (d >= lo && d < hi) {
      int s = src[e];
      int pos = atomicAdd(&cursor[d], 1);
      epair[pos] = make_int2(s, __float_as_int(dis[s]));
    }
  }
}

#define UNPACK_FMA(q, d)                                              \
  a0 = fmaf(__uint_as_float((q).x << 16), (d), a0);                   \
  a1 = fmaf(__uint_as_float((q).x & 0xffff0000u), (d), a1);           \
  a2 = fmaf(__uint_as_float((q).y << 16), (d), a2);                   \
  a3 = fmaf(__uint_as_float((q).y & 0xffff0000u), (d), a3);           \
  a4 = fmaf(__uint_as_float((q).z << 16), (d), a4);                   \
  a5 = fmaf(__uint_as_float((q).z & 0xffff0000u), (d), a5);           \
  a6 = fmaf(__uint_as_float((q).w << 16), (d), a6);                   \
  a7 = fmaf(__uint_as_float((q).w & 0xffff0000u), (d), a7);

// ---- fused layer: aggregate (bf16 gathers) + in-LDS GEMM + bias + relu ----
// One wave per node. W staged to LDS once per block (16KB, coalesced).
// After the butterfly reduce, the wave writes its 64-f32 row to a PER-WAVE
// LDS rowbuf (no block barrier needed), then computes
//   out[col=lane] = relu( sum_k row[k] * Ws[k][lane] + b[lane] ).
// Ws[k][lane] = 64 consecutive floats -> 2-way bank alias (free);
// rowbuf[k] = uniform broadcast (free).
// LAST: dot with Wl, wave-reduce, write scalar ynode[node] (no atomics).
template <int LAST>
__global__ __launch_bounds__(256) void fused_layer(const u16* __restrict__ Fh,
    const int* __restrict__ rowptr, const int2* __restrict__ epair,
    const float* __restrict__ dis, const float* __restrict__ W,
    const float* __restrict__ b, u16* __restrict__ FhOut,
    const float* __restrict__ Wl, float* __restrict__ ynode, int N) {
  __shared__ float Ws[DIM][DIM];      // 16 KB: Ws[k][col] = W row-major copy
  __shared__ float rowbuf[4][DIM];    // per-wave aggregated row

  // stage W (coalesced float4 copy)
  for (int i = threadIdx.x; i < DIM * DIM / 4; i += 256)
    reinterpret_cast<float4*>(&Ws[0][0])[i] = reinterpret_cast<const float4*>(W)[i];
  __syncthreads();

  int lane = threadIdx.x & 63;
  int wid = threadIdx.x >> 6;
  int node = blockIdx.x * 4 + wid;
  if (node >= N) return;
  int qc = lane & 7;    // 16B chunk index within 128B bf16 row
  int qe = lane >> 3;   // edge slot 0..7
  const uint4* __restrict__ F8 = reinterpret_cast<const uint4*>(Fh);

  float bias = b[lane];
  float wl = LAST ? Wl[lane] : 0.f;

  int beg = rowptr[node], end = rowptr[node + 1];
  float a0 = 0.f, a1 = 0.f, a2 = 0.f, a3 = 0.f;
  float a4 = 0.f, a5 = 0.f, a6 = 0.f, a7 = 0.f;
  int j = beg;
  for (; j + 16 <= end; j += 16) {
    int2 p0 = epair[j + qe];
    int2 p1 = epair[j + 8 + qe];
    uint4 q0 = F8[(size_t)p0.x * 8 + qc];
    uint4 q1 = F8[(size_t)p1.x * 8 + qc];
    float d0 = __int_as_float(p0.y), d1 = __int_as_float(p1.y);
    UNPACK_FMA(q0, d0)
    UNPACK_FMA(q1, d1)
  }
  if (j + 8 <= end) {
    int2 p0 = epair[j + qe];
    uint4 q0 = F8[(size_t)p0.x * 8 + qc];
    float d0 = __int_as_float(p0.y);
    UNPACK_FMA(q0, d0)
    j += 8;
  }
  if (j + qe < end) {
    int2 p0 = epair[j + qe];
    uint4 q0 = F8[(size_t)p0.x * 8 + qc];
    float d0 = __int_as_float(p0.y);
    UNPACK_FMA(q0, d0)
  }
  // butterfly over edge-slot bits 3..5: all lanes end with the chunk sums
  #pragma unroll
  for (int m = 8; m < 64; m <<= 1) {
    a0 += __shfl_xor(a0, m, 64); a1 += __shfl_xor(a1, m, 64);
    a2 += __shfl_xor(a2, m, 64); a3 += __shfl_xor(a3, m, 64);
    a4 += __shfl_xor(a4, m, 64); a5 += __shfl_xor(a5, m, 64);
    a6 += __shfl_xor(a6, m, 64); a7 += __shfl_xor(a7, m, 64);
  }
  // self-loop + symmetric scaling; lanes qe==0 write the row to LDS
  if (qe == 0) {
    float dn = dis[node];
    uint4 qs = F8[(size_t)node * 8 + qc];
    float s0 = __uint_as_float(qs.x << 16), s1 = __uint_as_float(qs.x & 0xffff0000u);
    float s2 = __uint_as_float(qs.y << 16), s3 = __uint_as_float(qs.y & 0xffff0000u);
    float s4 = __uint_as_float(qs.z << 16), s5 = __uint_as_float(qs.z & 0xffff0000u);
    float s6 = __uint_as_float(qs.w << 16), s7 = __uint_as_float(qs.w & 0xffff0000u);
    float4 o0, o1;
    o0.x = (a0 + s0 * dn) * dn; o0.y = (a1 + s1 * dn) * dn;
    o0.z = (a2 + s2 * dn) * dn; o0.w = (a3 + s3 * dn) * dn;
    o1.x = (a4 + s4 * dn) * dn; o1.y = (a5 + s5 * dn) * dn;
    o1.z = (a6 + s6 * dn) * dn; o1.w = (a7 + s7 * dn) * dn;
    float4* rb = reinterpret_cast<float4*>(&rowbuf[wid][qc * 8]);
    rb[0] = o0;
    rb[1] = o1;
  }
  // same-wave LDS write->read: compiler inserts the lgkmcnt wait; no barrier.
  float acc = bias;
  #pragma unroll 8
  for (int k = 0; k < DIM; ++k)
    acc = fmaf(rowbuf[wid][k], Ws[k][lane], acc);
  float v = fmaxf(acc, 0.f);
  if (!LAST) {
    FhOut[(size_t)node * DIM + lane] = bf16_rne(v);
  } else {
    float y = v * wl;
    #pragma unroll
    for (int off = 32; off > 0; off >>= 1) y += __shfl_down(y, off, 64);
    if (lane == 0) ynode[node] = y;
  }
}

// ---- pool: out[g] = mean over graph-g nodes of ynode + bl ----
__global__ void pool_final_kernel(const float* __restrict__ ynode, const int* __restrict__ batch,
                                  const float* __restrict__ bl, float* __restrict__ out, int N) {
  __shared__ float wsums[4];
  int g = blockIdx.x;
  int lo = 0, hi = N;
  while (lo < hi) { int m = (lo + hi) >> 1; if (batch[m] < g) lo = m + 1; else hi = m; }
  int start = lo;
  hi = N;
  while (lo < hi) { int m = (lo + hi) >> 1; if (batch[m] < g + 1) lo = m + 1; else hi = m; }
  int end = lo;
  float acc = 0.f;
  for (int i = start + threadIdx.x; i < end; i += 256) acc += ynode[i];
  #pragma unroll
  for (int off = 32; off > 0; off >>= 1) acc += __shfl_down(acc, off, 64);
  int lane = threadIdx.x & 63, wid = threadIdx.x >> 6;
  if (lane == 0) wsums[wid] = acc;
  __syncthreads();
  if (threadIdx.x == 0) {
    float s = wsums[0] + wsums[1] + wsums[2] + wsums[3];
    float c = fmaxf((float)(end - start), 1.f);
    out[g] = s / c + bl[0];
  }
}

extern "C" void kernel_launch(void* const* d_in, const int* in_sizes, int n_in,
                              void* d_out, int out_size, void* d_ws, size_t ws_size,
                              hipStream_t stream) {
  const float* x     = (const float*)d_in[0];
  const int*   ei    = (const int*)d_in[1];   // int64 in reference, delivered as int32
  const int*   batch = (const int*)d_in[2];
  const float* W1 = (const float*)d_in[3];
  const float* b1 = (const float*)d_in[4];
  const float* W2 = (const float*)d_in[5];
  const float* b2 = (const float*)d_in[6];
  const float* W3 = (const float*)d_in[7];
  const float* b3 = (const float*)d_in[8];
  const float* Wl = (const float*)d_in[9];
  const float* bl = (const float*)d_in[10];
  float* out = (float*)d_out;

  const int* srcp = ei;
  const int* dstp = ei + N_EDGES;

  char* ws = (char*)d_ws;
  size_t off = 0;
  auto alloc = [&](size_t bytes) { void* p = ws + off; off += (bytes + 255) & ~(size_t)255; return p; };
  int*   cnt     = (int*)  alloc((size_t)N_NODES * 4);        // reused as cursor
  float* dis     = (float*)alloc((size_t)N_NODES * 4);
  int*   rowptr  = (int*)  alloc((size_t)(N_NODES + 1) * 4);
  int*   bsum    = (int*)  alloc(64 * 4);
  float* ynode   = (float*)alloc((size_t)N_NODES * 4);
  int2*  epair   = (int2*) alloc((size_t)N_EDGES * 8);
  u16*   xh      = (u16*)  alloc((size_t)N_NODES * DIM * 2);  // bf16 feats (also layer-2 out)
  u16*   fh      = (u16*)  alloc((size_t)N_NODES * DIM * 2);  // bf16 layer-1 out

  const int NB = (N_NODES + 1023) / 1024;  // 49

  // ---- CSR build ----
  init_kernel<<<(N_NODES + 255) / 256, 256, 0, stream>>>(cnt, x, xh);
  count_deg_kernel<<<1024, 256, 0, stream>>>(dstp, cnt, N_EDGES);
  scanA_kernel<<<NB, 1024, 0, stream>>>(cnt, rowptr, bsum, dis, N_NODES);
  scanC_kernel<<<NB, 1024, 0, stream>>>(rowptr, bsum, cnt, NB, N_NODES);
  fill_kernel<<<1024, 256, 0, stream>>>(srcp, dstp, dis, cnt, epair, N_EDGES);

  // ---- 3 fused GCN layers (aggregate + GEMM in one kernel) ----
  const int AB = (N_NODES + 3) / 4;
  fused_layer<0><<<AB, 256, 0, stream>>>(xh, rowptr, epair, dis, W1, b1, fh,
                                         nullptr, nullptr, N_NODES);
  fused_layer<0><<<AB, 256, 0, stream>>>(fh, rowptr, epair, dis, W2, b2, xh,
                                         nullptr, nullptr, N_NODES);
  fused_layer<1><<<AB, 256, 0, stream>>>(xh, rowptr, epair, dis, W3, b3, nullptr,
                                         Wl, ynode, N_NODES);
  pool_final_kernel<<<NUM_GRAPHS, 256, 0, stream>>>(ynode, batch, bl, out, N_NODES);
}

// Round 14
// 225.956 us; speedup vs baseline: 1.0653x; 1.0653x over previous
//
#include <hip/hip_runtime.h>

#define N_NODES 50000
#define N_EDGES 800000
#define DIM 64
#define NUM_GRAPHS 64
#define NPART 8
#define PART_NODES 6250   // N_NODES / NPART exactly

typedef unsigned short u16;
typedef unsigned int u32;

__device__ __forceinline__ u16 bf16_rne(float f) {
  u32 u = __float_as_uint(f);
  u32 r = (u + 0x7fffu + ((u >> 16) & 1u)) >> 16;
  return (u16)r;
}

// ---- init: zero cnt + convert x -> bf16 ----
__global__ void init_kernel(int* __restrict__ cnt,
                            const float* __restrict__ x, u16* __restrict__ xh) {
  int i = blockIdx.x * blockDim.x + threadIdx.x;
  if (i < N_NODES) cnt[i] = 0;
  int stride = gridDim.x * blockDim.x;
  for (int k = i; k < N_NODES * DIM / 4; k += stride) {
    float4 v = reinterpret_cast<const float4*>(x)[k];
    ushort4 o;
    o.x = bf16_rne(v.x); o.y = bf16_rne(v.y);
    o.z = bf16_rne(v.z); o.w = bf16_rne(v.w);
    reinterpret_cast<ushort4*>(xh)[k] = o;
  }
}

// ---- degree count: single pass, grid-stride ----
__global__ void count_deg_kernel(const int* __restrict__ dst, int* __restrict__ cnt, int E) {
  int stride = gridDim.x * blockDim.x;
  for (int e = blockIdx.x * blockDim.x + threadIdx.x; e < E; e += stride)
    atomicAdd(&cnt[dst[e]], 1);
}

// ---- scan phase A: block-local exclusive scan of cnt, block sums, fused dis ----
__global__ void scanA_kernel(const int* __restrict__ cnt, int* __restrict__ rowptr,
                             int* __restrict__ bsum, float* __restrict__ dis, int N) {
  __shared__ int wsum[16];
  int i = blockIdx.x * 1024 + threadIdx.x;
  int lane = threadIdx.x & 63, wid = threadIdx.x >> 6;
  int v = (i < N) ? cnt[i] : 0;
  if (i < N) dis[i] = rsqrtf((float)(v + 1));
  int sv = v;
  #pragma unroll
  for (int off = 1; off < 64; off <<= 1) {
    int t = __shfl_up(sv, off, 64);
    if (lane >= off) sv += t;
  }
  if (lane == 63) wsum[wid] = sv;
  __syncthreads();
  if (wid == 0) {
    int wv = (lane < 16) ? wsum[lane] : 0;
    #pragma unroll
    for (int off = 1; off < 16; off <<= 1) {
      int t = __shfl_up(wv, off, 64);
      if (lane >= off) wv += t;
    }
    if (lane < 16) wsum[lane] = wv;
  }
  __syncthreads();
  if (i < N) rowptr[i] = (wid ? wsum[wid - 1] : 0) + (sv - v);
  if (threadIdx.x == 1023) bsum[blockIdx.x] = wsum[15];
}

// ---- scan phase C (B folded in) ----
__global__ void scanC_kernel(int* __restrict__ rowptr, const int* __restrict__ bsum,
                             int* __restrict__ cursor, int nb, int N) {
  __shared__ int s_off;
  __shared__ int s_total;
  int b = blockIdx.x;
  if (threadIdx.x < 64) {
    int t = threadIdx.x;
    int v = (t < nb) ? bsum[t] : 0;
    #pragma unroll
    for (int off = 1; off < 64; off <<= 1) {
      int u = __shfl_up(v, off, 64);
      if (t >= off) v += u;
    }
    if (t == (b == 0 ? 0 : b - 1)) s_off = (b == 0) ? 0 : v;
    if (t == nb - 1) s_total = v;
  }
  __syncthreads();
  int i = b * 1024 + threadIdx.x;
  if (i < N) {
    int r = rowptr[i] + s_off;
    rowptr[i] = r;
    cursor[i] = r;
  }
  if (b == 0 && threadIdx.x == 0) rowptr[N] = s_total;
}

// ---- fill CSR, XCD-partitioned; stores bare src (4B) to halve scatter ----
__global__ void fill_kernel(const int* __restrict__ src, const int* __restrict__ dst,
                            int* __restrict__ cursor, int* __restrict__ esrc, int E) {
  int p = blockIdx.x & 7;
  int lo = p * PART_NODES, hi = lo + PART_NODES;
  int stride = (gridDim.x >> 3) * blockDim.x;
  for (int e = (blockIdx.x >> 3) * blockDim.x + threadIdx.x; e < E; e += stride) {
    int d = dst[e];
    if (d >= lo && d < hi) {
      int s = src[e];
      int pos = atomicAdd(&cursor[d], 1);
      esrc[pos] = s;
    }
  }
}

#define UNPACK_FMA(q, d)                                              \
  a0 = fmaf(__uint_as_float((q).x << 16), (d), a0);                   \
  a1 = fmaf(__uint_as_float((q).x & 0xffff0000u), (d), a1);           \
  a2 = fmaf(__uint_as_float((q).y << 16), (d), a2);                   \
  a3 = fmaf(__uint_as_float((q).y & 0xffff0000u), (d), a3);           \
  a4 = fmaf(__uint_as_float((q).z << 16), (d), a4);                   \
  a5 = fmaf(__uint_as_float((q).z & 0xffff0000u), (d), a5);           \
  a6 = fmaf(__uint_as_float((q).w << 16), (d), a6);                   \
  a7 = fmaf(__uint_as_float((q).w & 0xffff0000u), (d), a7);

// ---- aggregate (bf16 features): A_i = dis_i*(sum dis_j*F_j + dis_i*F_i) ----
// one wave per node; 8 lanes x 16B cover a 128B bf16 row; 8 edge slots.
__global__ __launch_bounds__(256) void aggregate_kernel(const u16* __restrict__ Fh,
    const int* __restrict__ rowptr, const int* __restrict__ esrc,
    const float* __restrict__ dis, float* __restrict__ A, int N) {
  int node = blockIdx.x * 4 + (threadIdx.x >> 6);
  if (node >= N) return;
  int lane = threadIdx.x & 63;
  int qc = lane & 7;    // 16B chunk index within 128B row (8 bf16 cols)
  int qe = lane >> 3;   // edge slot 0..7
  const uint4* __restrict__ F8 = reinterpret_cast<const uint4*>(Fh);
  int beg = rowptr[node], end = rowptr[node + 1];
  float a0 = 0.f, a1 = 0.f, a2 = 0.f, a3 = 0.f;
  float a4 = 0.f, a5 = 0.f, a6 = 0.f, a7 = 0.f;
  int j = beg;
  for (; j + 16 <= end; j += 16) {
    int s0 = esrc[j + qe];
    int s1 = esrc[j + 8 + qe];
    float d0 = dis[s0], d1 = dis[s1];
    uint4 q0 = F8[(size_t)s0 * 8 + qc];
    uint4 q1 = F8[(size_t)s1 * 8 + qc];
    UNPACK_FMA(q0, d0)
    UNPACK_FMA(q1, d1)
  }
  if (j + 8 <= end) {
    int s0 = esrc[j + qe];
    float d0 = dis[s0];
    uint4 q0 = F8[(size_t)s0 * 8 + qc];
    UNPACK_FMA(q0, d0)
    j += 8;
  }
  if (j + qe < end) {
    int s0 = esrc[j + qe];
    float d0 = dis[s0];
    uint4 q0 = F8[(size_t)s0 * 8 + qc];
    UNPACK_FMA(q0, d0)
  }
  // reduce the 8 edge-slot groups (lanes differ in bits 3..5)
  #pragma unroll
  for (int m = 8; m < 64; m <<= 1) {
    a0 += __shfl_xor(a0, m, 64); a1 += __shfl_xor(a1, m, 64);
    a2 += __shfl_xor(a2, m, 64); a3 += __shfl_xor(a3, m, 64);
    a4 += __shfl_xor(a4, m, 64); a5 += __shfl_xor(a5, m, 64);
    a6 += __shfl_xor(a6, m, 64); a7 += __shfl_xor(a7, m, 64);
  }
  if (qe == 0) {
    float dn = dis[node];
    uint4 qs = F8[(size_t)node * 8 + qc];
    float s0 = __uint_as_float(qs.x << 16), s1 = __uint_as_float(qs.x & 0xffff0000u);
    float s2 = __uint_as_float(qs.y << 16), s3 = __uint_as_float(qs.y & 0xffff0000u);
    float s4 = __uint_as_float(qs.z << 16), s5 = __uint_as_float(qs.z & 0xffff0000u);
    float s6 = __uint_as_float(qs.w << 16), s7 = __uint_as_float(qs.w & 0xffff0000u);
    float4 o0, o1;
    o0.x = (a0 + s0 * dn) * dn; o0.y = (a1 + s1 * dn) * dn;
    o0.z = (a2 + s2 * dn) * dn; o0.w = (a3 + s3 * dn) * dn;
    o1.x = (a4 + s4 * dn) * dn; o1.y = (a5 + s5 * dn) * dn;
    o1.z = (a6 + s6 * dn) * dn; o1.w = (a7 + s7 * dn) * dn;
    float4* A4 = reinterpret_cast<float4*>(A + (size_t)node * DIM + qc * 8);
    A4[0] = o0;
    A4[1] = o1;
  }
}

// ---- fused GEMM + bias + relu; writes bf16 for the next aggregate ----
__global__ __launch_bounds__(256) void gemm_bias_relu(const float* __restrict__ X,
    const float* __restrict__ W, const float* __restrict__ b,
    u16* __restrict__ Fh, int N) {
  __shared__ float4 Xs[64][16];
  int col = threadIdx.x & 63, wid = threadIdx.x >> 6;
  float wreg[DIM];
  #pragma unroll
  for (int k = 0; k < DIM; ++k) wreg[k] = W[k * DIM + col];
  float bias = b[col];
  int row0 = blockIdx.x * 64;
  for (int i = threadIdx.x; i < 64 * 16; i += 256) {
    int r = i >> 4, c = i & 15;
    int gr = row0 + r;
    Xs[r][c] = (gr < N) ? reinterpret_cast<const float4*>(X)[(size_t)gr * 16 + c]
                        : make_float4(0.f, 0.f, 0.f, 0.f);
  }
  __syncthreads();
  for (int rr = 0; rr < 16; ++rr) {
    int lr = wid * 16 + rr;
    int row = row0 + lr;
    if (row >= N) break;   // uniform per wave
    float a0 = 0.f, a1 = 0.f, a2 = 0.f, a3 = 0.f;
    #pragma unroll
    for (int kk = 0; kk < 16; ++kk) {
      float4 xv = Xs[lr][kk];
      a0 = fmaf(xv.x, wreg[4 * kk + 0], a0);
      a1 = fmaf(xv.y, wreg[4 * kk + 1], a1);
      a2 = fmaf(xv.z, wreg[4 * kk + 2], a2);
      a3 = fmaf(xv.w, wreg[4 * kk + 3], a3);
    }
    float v = fmaxf(a0 + a1 + a2 + a3 + bias, 0.f);
    Fh[(size_t)row * DIM + col] = bf16_rne(v);
  }
}

// ---- layer-3 fused: y = relu(A@W3+b3) . Wl, block-level graph partials ----
__global__ __launch_bounds__(256) void gemm_dot_kernel(const float* __restrict__ X,
    const float* __restrict__ W, const float* __restrict__ b, const float* __restrict__ Wl,
    const int* __restrict__ batch, float* __restrict__ partial, int N) {
  __shared__ float4 Xs[64][16];
  __shared__ float yv[64];
  __shared__ float gpart[NUM_GRAPHS];
  int col = threadIdx.x & 63, wid = threadIdx.x >> 6;
  float wreg[DIM];
  #pragma unroll
  for (int k = 0; k < DIM; ++k) wreg[k] = W[k * DIM + col];
  float bias = b[col];
  float wl = Wl[col];
  int row0 = blockIdx.x * 64;
  if (threadIdx.x < 64) { yv[threadIdx.x] = 0.f; gpart[threadIdx.x] = 0.f; }
  for (int i = threadIdx.x; i < 64 * 16; i += 256) {
    int r = i >> 4, c = i & 15;
    int gr = row0 + r;
    Xs[r][c] = (gr < N) ? reinterpret_cast<const float4*>(X)[(size_t)gr * 16 + c]
                        : make_float4(0.f, 0.f, 0.f, 0.f);
  }
  __syncthreads();
  for (int rr = 0; rr < 16; ++rr) {
    int lr = wid * 16 + rr;
    int row = row0 + lr;
    if (row >= N) break;   // uniform per wave
    float a0 = 0.f, a1 = 0.f, a2 = 0.f, a3 = 0.f;
    #pragma unroll
    for (int kk = 0; kk < 16; ++kk) {
      float4 xv = Xs[lr][kk];
      a0 = fmaf(xv.x, wreg[4 * kk + 0], a0);
      a1 = fmaf(xv.y, wreg[4 * kk + 1], a1);
      a2 = fmaf(xv.z, wreg[4 * kk + 2], a2);
      a3 = fmaf(xv.w, wreg[4 * kk + 3], a3);
    }
    float v = fmaxf(a0 + a1 + a2 + a3 + bias, 0.f);
    float y = v * wl;
    #pragma unroll
    for (int off = 32; off > 0; off >>= 1) y += __shfl_down(y, off, 64);
    if (col == 0) yv[lr] = y;
  }
  __syncthreads();
  if (threadIdx.x < 64) {
    int row = row0 + threadIdx.x;
    if (row < N) atomicAdd(&gpart[batch[row]], yv[threadIdx.x]);
  }
  __syncthreads();
  if (threadIdx.x < NUM_GRAPHS) {
    int glo = batch[row0];
    int ghi = batch[min(row0 + 63, N - 1)];
    int g = threadIdx.x;
    if (g >= glo && g <= ghi) atomicAdd(&partial[g], gpart[g]);
  }
}

// ---- finalize: out[g] = partial[g]/count_g + bl ----
__global__ void pool_final_kernel(const float* __restrict__ partial, const int* __restrict__ batch,
                                  const float* __restrict__ bl, float* __restrict__ out, int N) {
  int g = threadIdx.x;  // 64 threads
  int lo = 0, hi = N;
  while (lo < hi) { int m = (lo + hi) >> 1; if (batch[m] < g) lo = m + 1; else hi = m; }
  int start = lo;
  hi = N;
  while (lo < hi) { int m = (lo + hi) >> 1; if (batch[m] < g + 1) lo = m + 1; else hi = m; }
  float c = fmaxf((float)(lo - start), 1.f);
  out[g] = partial[g] / c + bl[0];
}

extern "C" void kernel_launch(void* const* d_in, const int* in_sizes, int n_in,
                              void* d_out, int out_size, void* d_ws, size_t ws_size,
                              hipStream_t stream) {
  const float* x     = (const float*)d_in[0];
  const int*   ei    = (const int*)d_in[1];   // int64 in reference, delivered as int32
  const int*   batch = (const int*)d_in[2];
  const float* W1 = (const float*)d_in[3];
  const float* b1 = (const float*)d_in[4];
  const float* W2 = (const float*)d_in[5];
  const float* b2 = (const float*)d_in[6];
  const float* W3 = (const float*)d_in[7];
  const float* b3 = (const float*)d_in[8];
  const float* Wl = (const float*)d_in[9];
  const float* bl = (const float*)d_in[10];
  float* out = (float*)d_out;

  const int* srcp = ei;
  const int* dstp = ei + N_EDGES;

  char* ws = (char*)d_ws;
  size_t off = 0;
  auto alloc = [&](size_t bytes) { void* p = ws + off; off += (bytes + 255) & ~(size_t)255; return p; };
  int*   cnt     = (int*)  alloc((size_t)N_NODES * 4);        // reused as cursor
  float* dis     = (float*)alloc((size_t)N_NODES * 4);
  int*   rowptr  = (int*)  alloc((size_t)(N_NODES + 1) * 4);
  int*   bsum    = (int*)  alloc(64 * 4);
  float* partial = (float*)alloc(NUM_GRAPHS * 4);
  int*   esrc    = (int*)  alloc((size_t)N_EDGES * 4);
  u16*   xh      = (u16*)  alloc((size_t)N_NODES * DIM * 2);  // bf16 feats (also layer-2 out)
  u16*   fh      = (u16*)  alloc((size_t)N_NODES * DIM * 2);  // bf16 layer-1 out
  float* A       = (float*)alloc((size_t)N_NODES * DIM * 4);  // f32 aggregate output

  const int NB = (N_NODES + 1023) / 1024;  // 49

  // ---- CSR build ----
  init_kernel<<<(N_NODES + 255) / 256, 256, 0, stream>>>(cnt, x, xh);
  count_deg_kernel<<<1024, 256, 0, stream>>>(dstp, cnt, N_EDGES);
  scanA_kernel<<<NB, 1024, 0, stream>>>(cnt, rowptr, bsum, dis, N_NODES);
  scanC_kernel<<<NB, 1024, 0, stream>>>(rowptr, bsum, cnt, NB, N_NODES);
  fill_kernel<<<1024, 256, 0, stream>>>(srcp, dstp, cnt, esrc, N_EDGES);

  // ---- 3 GCN layers (bf16 gathers, f32 accumulate/GEMM) ----
  const int GB = (N_NODES + 63) / 64;  // 782
  const int AB = (N_NODES + 3) / 4;
  // zero partial (reuse init slot? tiny: do inside pool path) -- partial zeroed here:
  hipMemsetAsync(partial, 0, NUM_GRAPHS * 4, stream);
  aggregate_kernel<<<AB, 256, 0, stream>>>(xh, rowptr, esrc, dis, A, N_NODES);
  gemm_bias_relu<<<GB, 256, 0, stream>>>(A, W1, b1, fh, N_NODES);
  aggregate_kernel<<<AB, 256, 0, stream>>>(fh, rowptr, esrc, dis, A, N_NODES);
  gemm_bias_relu<<<GB, 256, 0, stream>>>(A, W2, b2, xh, N_NODES);   // reuse xh
  aggregate_kernel<<<AB, 256, 0, stream>>>(xh, rowptr, esrc, dis, A, N_NODES);
  gemm_dot_kernel<<<GB, 256, 0, stream>>>(A, W3, b3, Wl, batch, partial, N_NODES);
  pool_final_kernel<<<1, 64, 0, stream>>>(partial, batch, bl, out, N_NODES);
}

// Round 15
// 224.851 us; speedup vs baseline: 1.0705x; 1.0049x over previous
//
#include <hip/hip_runtime.h>

#define N_NODES 50000
#define N_EDGES 800000
#define DIM 64
#define NUM_GRAPHS 64
#define NPART 8
#define PART_NODES 6250   // N_NODES / NPART exactly

typedef unsigned short u16;
typedef unsigned int u32;

__device__ __forceinline__ u16 bf16_rne(float f) {
  u32 u = __float_as_uint(f);
  u32 r = (u + 0x7fffu + ((u >> 16) & 1u)) >> 16;
  return (u16)r;
}

// ---- init: zero cnt/partial + convert x -> bf16 ----
__global__ void init_kernel(int* __restrict__ cnt, float* __restrict__ partial,
                            const float* __restrict__ x, u16* __restrict__ xh) {
  int i = blockIdx.x * blockDim.x + threadIdx.x;
  if (i < N_NODES) cnt[i] = 0;
  if (i < NUM_GRAPHS) partial[i] = 0.f;
  int stride = gridDim.x * blockDim.x;
  for (int k = i; k < N_NODES * DIM / 4; k += stride) {
    float4 v = reinterpret_cast<const float4*>(x)[k];
    ushort4 o;
    o.x = bf16_rne(v.x); o.y = bf16_rne(v.y);
    o.z = bf16_rne(v.z); o.w = bf16_rne(v.w);
    reinterpret_cast<ushort4*>(xh)[k] = o;
  }
}

// ---- pack edges to u32 (src<<16|dst) + count degrees, single pass ----
__global__ void pack_count_kernel(const int* __restrict__ src, const int* __restrict__ dst,
                                  u32* __restrict__ epk, int* __restrict__ cnt, int E) {
  int stride = gridDim.x * blockDim.x;
  for (int e = blockIdx.x * blockDim.x + threadIdx.x; e < E; e += stride) {
    int d = dst[e];
    int s = src[e];
    epk[e] = ((u32)s << 16) | (u32)d;
    atomicAdd(&cnt[d], 1);
  }
}

// ---- scan phase A: block-local exclusive scan of cnt, block sums, fused dis ----
__global__ void scanA_kernel(const int* __restrict__ cnt, int* __restrict__ rowptr,
                             int* __restrict__ bsum, float* __restrict__ dis, int N) {
  __shared__ int wsum[16];
  int i = blockIdx.x * 1024 + threadIdx.x;
  int lane = threadIdx.x & 63, wid = threadIdx.x >> 6;
  int v = (i < N) ? cnt[i] : 0;
  if (i < N) dis[i] = rsqrtf((float)(v + 1));
  int sv = v;
  #pragma unroll
  for (int off = 1; off < 64; off <<= 1) {
    int t = __shfl_up(sv, off, 64);
    if (lane >= off) sv += t;
  }
  if (lane == 63) wsum[wid] = sv;
  __syncthreads();
  if (wid == 0) {
    int wv = (lane < 16) ? wsum[lane] : 0;
    #pragma unroll
    for (int off = 1; off < 16; off <<= 1) {
      int t = __shfl_up(wv, off, 64);
      if (lane >= off) wv += t;
    }
    if (lane < 16) wsum[lane] = wv;
  }
  __syncthreads();
  if (i < N) rowptr[i] = (wid ? wsum[wid - 1] : 0) + (sv - v);
  if (threadIdx.x == 1023) bsum[blockIdx.x] = wsum[15];
}

// ---- scan phase C (B folded in) ----
__global__ void scanC_kernel(int* __restrict__ rowptr, const int* __restrict__ bsum,
                             int* __restrict__ cursor, int nb, int N) {
  __shared__ int s_off;
  __shared__ int s_total;
  int b = blockIdx.x;
  if (threadIdx.x < 64) {
    int t = threadIdx.x;
    int v = (t < nb) ? bsum[t] : 0;
    #pragma unroll
    for (int off = 1; off < 64; off <<= 1) {
      int u = __shfl_up(v, off, 64);
      if (t >= off) v += u;
    }
    if (t == (b == 0 ? 0 : b - 1)) s_off = (b == 0) ? 0 : v;
    if (t == nb - 1) s_total = v;
  }
  __syncthreads();
  int i = b * 1024 + threadIdx.x;
  if (i < N) {
    int r = rowptr[i] + s_off;
    rowptr[i] = r;
    cursor[i] = r;
  }
  if (b == 0 && threadIdx.x == 0) rowptr[N] = s_total;
}

// ---- fill CSR, XCD-partitioned; streams 3.2MB packed edges (fits L2
// alongside the 400KB scatter window -> minimal writeback thrash) ----
__global__ void fill_kernel(const u32* __restrict__ epk,
                            int* __restrict__ cursor, int* __restrict__ esrc, int E) {
  int p = blockIdx.x & 7;
  int lo = p * PART_NODES, hi = lo + PART_NODES;
  int stride = (gridDim.x >> 3) * blockDim.x;
  for (int e = (blockIdx.x >> 3) * blockDim.x + threadIdx.x; e < E; e += stride) {
    u32 rec = epk[e];
    int d = (int)(rec & 0xffffu);
    if (d >= lo && d < hi) {
      int pos = atomicAdd(&cursor[d], 1);
      esrc[pos] = (int)(rec >> 16);
    }
  }
}

#define UNPACK_FMA(q, d)                                              \
  a0 = fmaf(__uint_as_float((q).x << 16), (d), a0);                   \
  a1 = fmaf(__uint_as_float((q).x & 0xffff0000u), (d), a1);           \
  a2 = fmaf(__uint_as_float((q).y << 16), (d), a2);                   \
  a3 = fmaf(__uint_as_float((q).y & 0xffff0000u), (d), a3);           \
  a4 = fmaf(__uint_as_float((q).z << 16), (d), a4);                   \
  a5 = fmaf(__uint_as_float((q).z & 0xffff0000u), (d), a5);           \
  a6 = fmaf(__uint_as_float((q).w << 16), (d), a6);                   \
  a7 = fmaf(__uint_as_float((q).w & 0xffff0000u), (d), a7);

// ---- aggregate (bf16 features): A_i = dis_i*(sum dis_j*F_j + dis_i*F_i) ----
__global__ __launch_bounds__(256) void aggregate_kernel(const u16* __restrict__ Fh,
    const int* __restrict__ rowptr, const int* __restrict__ esrc,
    const float* __restrict__ dis, float* __restrict__ A, int N) {
  int node = blockIdx.x * 4 + (threadIdx.x >> 6);
  if (node >= N) return;
  int lane = threadIdx.x & 63;
  int qc = lane & 7;    // 16B chunk index within 128B row (8 bf16 cols)
  int qe = lane >> 3;   // edge slot 0..7
  const uint4* __restrict__ F8 = reinterpret_cast<const uint4*>(Fh);
  int beg = rowptr[node], end = rowptr[node + 1];
  float a0 = 0.f, a1 = 0.f, a2 = 0.f, a3 = 0.f;
  float a4 = 0.f, a5 = 0.f, a6 = 0.f, a7 = 0.f;
  int j = beg;
  for (; j + 16 <= end; j += 16) {
    int s0 = esrc[j + qe];
    int s1 = esrc[j + 8 + qe];
    float d0 = dis[s0], d1 = dis[s1];
    uint4 q0 = F8[(size_t)s0 * 8 + qc];
    uint4 q1 = F8[(size_t)s1 * 8 + qc];
    UNPACK_FMA(q0, d0)
    UNPACK_FMA(q1, d1)
  }
  if (j + 8 <= end) {
    int s0 = esrc[j + qe];
    float d0 = dis[s0];
    uint4 q0 = F8[(size_t)s0 * 8 + qc];
    UNPACK_FMA(q0, d0)
    j += 8;
  }
  if (j + qe < end) {
    int s0 = esrc[j + qe];
    float d0 = dis[s0];
    uint4 q0 = F8[(size_t)s0 * 8 + qc];
    UNPACK_FMA(q0, d0)
  }
  #pragma unroll
  for (int m = 8; m < 64; m <<= 1) {
    a0 += __shfl_xor(a0, m, 64); a1 += __shfl_xor(a1, m, 64);
    a2 += __shfl_xor(a2, m, 64); a3 += __shfl_xor(a3, m, 64);
    a4 += __shfl_xor(a4, m, 64); a5 += __shfl_xor(a5, m, 64);
    a6 += __shfl_xor(a6, m, 64); a7 += __shfl_xor(a7, m, 64);
  }
  if (qe == 0) {
    float dn = dis[node];
    uint4 qs = F8[(size_t)node * 8 + qc];
    float s0 = __uint_as_float(qs.x << 16), s1 = __uint_as_float(qs.x & 0xffff0000u);
    float s2 = __uint_as_float(qs.y << 16), s3 = __uint_as_float(qs.y & 0xffff0000u);
    float s4 = __uint_as_float(qs.z << 16), s5 = __uint_as_float(qs.z & 0xffff0000u);
    float s6 = __uint_as_float(qs.w << 16), s7 = __uint_as_float(qs.w & 0xffff0000u);
    float4 o0, o1;
    o0.x = (a0 + s0 * dn) * dn; o0.y = (a1 + s1 * dn) * dn;
    o0.z = (a2 + s2 * dn) * dn; o0.w = (a3 + s3 * dn) * dn;
    o1.x = (a4 + s4 * dn) * dn; o1.y = (a5 + s5 * dn) * dn;
    o1.z = (a6 + s6 * dn) * dn; o1.w = (a7 + s7 * dn) * dn;
    float4* A4 = reinterpret_cast<float4*>(A + (size_t)node * DIM + qc * 8);
    A4[0] = o0;
    A4[1] = o1;
  }
}

// ---- fused GEMM + bias + relu; writes bf16 for the next aggregate ----
__global__ __launch_bounds__(256) void gemm_bias_relu(const float* __restrict__ X,
    const float* __restrict__ W, const float* __restrict__ b,
    u16* __restrict__ Fh, int N) {
  __shared__ float4 Xs[64][16];
  int col = threadIdx.x & 63, wid = threadIdx.x >> 6;
  float wreg[DIM];
  #pragma unroll
  for (int k = 0; k < DIM; ++k) wreg[k] = W[k * DIM + col];
  float bias = b[col];
  int row0 = blockIdx.x * 64;
  for (int i = threadIdx.x; i < 64 * 16; i += 256) {
    int r = i >> 4, c = i & 15;
    int gr = row0 + r;
    Xs[r][c] = (gr < N) ? reinterpret_cast<const float4*>(X)[(size_t)gr * 16 + c]
                        : make_float4(0.f, 0.f, 0.f, 0.f);
  }
  __syncthreads();
  for (int rr = 0; rr < 16; ++rr) {
    int lr = wid * 16 + rr;
    int row = row0 + lr;
    if (row >= N) break;   // uniform per wave
    float a0 = 0.f, a1 = 0.f, a2 = 0.f, a3 = 0.f;
    #pragma unroll
    for (int kk = 0; kk < 16; ++kk) {
      float4 xv = Xs[lr][kk];
      a0 = fmaf(xv.x, wreg[4 * kk + 0], a0);
      a1 = fmaf(xv.y, wreg[4 * kk + 1], a1);
      a2 = fmaf(xv.z, wreg[4 * kk + 2], a2);
      a3 = fmaf(xv.w, wreg[4 * kk + 3], a3);
    }
    float v = fmaxf(a0 + a1 + a2 + a3 + bias, 0.f);
    Fh[(size_t)row * DIM + col] = bf16_rne(v);
  }
}

// ---- layer-3 fused: y = relu(A@W3+b3) . Wl, block-level graph partials ----
__global__ __launch_bounds__(256) void gemm_dot_kernel(const float* __restrict__ X,
    const float* __restrict__ W, const float* __restrict__ b, const float* __restrict__ Wl,
    const int* __restrict__ batch, float* __restrict__ partial, int N) {
  __shared__ float4 Xs[64][16];
  __shared__ float yv[64];
  __shared__ float gpart[NUM_GRAPHS];
  int col = threadIdx.x & 63, wid = threadIdx.x >> 6;
  float wreg[DIM];
  #pragma unroll
  for (int k = 0; k < DIM; ++k) wreg[k] = W[k * DIM + col];
  float bias = b[col];
  float wl = Wl[col];
  int row0 = blockIdx.x * 64;
  if (threadIdx.x < 64) { yv[threadIdx.x] = 0.f; gpart[threadIdx.x] = 0.f; }
  for (int i = threadIdx.x; i < 64 * 16; i += 256) {
    int r = i >> 4, c = i & 15;
    int gr = row0 + r;
    Xs[r][c] = (gr < N) ? reinterpret_cast<const float4*>(X)[(size_t)gr * 16 + c]
                        : make_float4(0.f, 0.f, 0.f, 0.f);
  }
  __syncthreads();
  for (int rr = 0; rr < 16; ++rr) {
    int lr = wid * 16 + rr;
    int row = row0 + lr;
    if (row >= N) break;   // uniform per wave
    float a0 = 0.f, a1 = 0.f, a2 = 0.f, a3 = 0.f;
    #pragma unroll
    for (int kk = 0; kk < 16; ++kk) {
      float4 xv = Xs[lr][kk];
      a0 = fmaf(xv.x, wreg[4 * kk + 0], a0);
      a1 = fmaf(xv.y, wreg[4 * kk + 1], a1);
      a2 = fmaf(xv.z, wreg[4 * kk + 2], a2);
      a3 = fmaf(xv.w, wreg[4 * kk + 3], a3);
    }
    float v = fmaxf(a0 + a1 + a2 + a3 + bias, 0.f);
    float y = v * wl;
    #pragma unroll
    for (int off = 32; off > 0; off >>= 1) y += __shfl_down(y, off, 64);
    if (col == 0) yv[lr] = y;
  }
  __syncthreads();
  if (threadIdx.x < 64) {
    int row = row0 + threadIdx.x;
    if (row < N) atomicAdd(&gpart[batch[row]], yv[threadIdx.x]);
  }
  __syncthreads();
  if (threadIdx.x < NUM_GRAPHS) {
    int glo = batch[row0];
    int ghi = batch[min(row0 + 63, N - 1)];
    int g = threadIdx.x;
    if (g >= glo && g <= ghi) atomicAdd(&partial[g], gpart[g]);
  }
}

// ---- finalize: out[g] = partial[g]/count_g + bl ----
__global__ void pool_final_kernel(const float* __restrict__ partial, const int* __restrict__ batch,
                                  const float* __restrict__ bl, float* __restrict__ out, int N) {
  int g = threadIdx.x;  // 64 threads
  int lo = 0, hi = N;
  while (lo < hi) { int m = (lo + hi) >> 1; if (batch[m] < g) lo = m + 1; else hi = m; }
  int start = lo;
  hi = N;
  while (lo < hi) { int m = (lo + hi) >> 1; if (batch[m] < g + 1) lo = m + 1; else hi = m; }
  float c = fmaxf((float)(lo - start), 1.f);
  out[g] = partial[g] / c + bl[0];
}

extern "C" void kernel_launch(void* const* d_in, const int* in_sizes, int n_in,
                              void* d_out, int out_size, void* d_ws, size_t ws_size,
                              hipStream_t stream) {
  const float* x     = (const float*)d_in[0];
  const int*   ei    = (const int*)d_in[1];   // int64 in reference, delivered as int32
  const int*   batch = (const int*)d_in[2];
  const float* W1 = (const float*)d_in[3];
  const float* b1 = (const float*)d_in[4];
  const float* W2 = (const float*)d_in[5];
  const float* b2 = (const float*)d_in[6];
  const float* W3 = (const float*)d_in[7];
  const float* b3 = (const float*)d_in[8];
  const float* Wl = (const float*)d_in[9];
  const float* bl = (const float*)d_in[10];
  float* out = (float*)d_out;

  const int* srcp = ei;
  const int* dstp = ei + N_EDGES;

  char* ws = (char*)d_ws;
  size_t off = 0;
  auto alloc = [&](size_t bytes) { void* p = ws + off; off += (bytes + 255) & ~(size_t)255; return p; };
  int*   cnt     = (int*)  alloc((size_t)N_NODES * 4);        // reused as cursor
  float* dis     = (float*)alloc((size_t)N_NODES * 4);
  int*   rowptr  = (int*)  alloc((size_t)(N_NODES + 1) * 4);
  int*   bsum    = (int*)  alloc(64 * 4);
  float* partial = (float*)alloc(NUM_GRAPHS * 4);
  u32*   epk     = (u32*)  alloc((size_t)N_EDGES * 4);
  int*   esrc    = (int*)  alloc((size_t)N_EDGES * 4);
  u16*   xh      = (u16*)  alloc((size_t)N_NODES * DIM * 2);  // bf16 feats (also layer-2 out)
  u16*   fh      = (u16*)  alloc((size_t)N_NODES * DIM * 2);  // bf16 layer-1 out
  float* A       = (float*)alloc((size_t)N_NODES * DIM * 4);  // f32 aggregate output

  const int NB = (N_NODES + 1023) / 1024;  // 49

  // ---- CSR build ----
  init_kernel<<<(N_NODES + 255) / 256, 256, 0, stream>>>(cnt, partial, x, xh);
  pack_count_kernel<<<1024, 256, 0, stream>>>(srcp, dstp, epk, cnt, N_EDGES);
  scanA_kernel<<<NB, 1024, 0, stream>>>(cnt, rowptr, bsum, dis, N_NODES);
  scanC_kernel<<<NB, 1024, 0, stream>>>(rowptr, bsum, cnt, NB, N_NODES);
  fill_kernel<<<1024, 256, 0, stream>>>(epk, cnt, esrc, N_EDGES);

  // ---- 3 GCN layers (bf16 gathers, f32 accumulate/GEMM) ----
  const int GB = (N_NODES + 63) / 64;  // 782
  const int AB = (N_NODES + 3) / 4;
  aggregate_kernel<<<AB, 256, 0, stream>>>(xh, rowptr, esrc, dis, A, N_NODES);
  gemm_bias_relu<<<GB, 256, 0, stream>>>(A, W1, b1, fh, N_NODES);
  aggregate_kernel<<<AB, 256, 0, stream>>>(fh, rowptr, esrc, dis, A, N_NODES);
  gemm_bias_relu<<<GB, 256, 0, stream>>>(A, W2, b2, xh, N_NODES);   // reuse xh
  aggregate_kernel<<<AB, 256, 0, stream>>>(xh, rowptr, esrc, dis, A, N_NODES);
  gemm_dot_kernel<<<GB, 256, 0, stream>>>(A, W3, b3, Wl, batch, partial, N_NODES);
  pool_final_kernel<<<1, 64, 0, stream>>>(partial, batch, bl, out, N_NODES);
}